// Round 1
// baseline (6718.284 us; speedup 1.0000x reference)
//
#include <hip/hip_runtime.h>

#define TSTEPS 20
constexpr float THRES = 1.0f;
constexpr float DECAY = 0.875f;  // (2^3-1)/2^3

constexpr int DIM_IN = 64;
constexpr int NIN = DIM_IN * DIM_IN;          // 4096
constexpr int C1 = 64, K1 = 7, D1 = 58;
constexpr int N1 = C1 * D1 * D1;              // 215296
constexpr int C2 = 128, K2 = 7, D2 = 52;
constexpr int N2 = C2 * D2 * D2;              // 346112
constexpr int NFLAT = N2;
constexpr int NHID = 512;
constexpr int NOUT = 10;

// Persistent state for the 20-step recurrence (zeroed every kernel_launch).
__device__ float g_mp_in[NIN];
__device__ float g_s_in[NIN];
__device__ float g_mp_c1[N1];
__device__ float g_sp_c1[N1];   // conv1 spikes (read by conv2 next step)
__device__ float g_mp_c2[N2];
__device__ float g_sp_c2[N2];   // conv2 spikes (read by linear1 next step)
__device__ float g_mp_l1[NHID];
__device__ float g_sp_l1[NHID]; // linear1 spikes (read by linear2 next step)
__device__ float g_mp_l2[NOUT];

__global__ void init_kernel(float* __restrict__ out) {
    int i = blockIdx.x * blockDim.x + threadIdx.x;
    int stride = gridDim.x * blockDim.x;
    for (int j = i; j < NIN; j += stride) { g_mp_in[j] = 0.f; g_s_in[j] = 0.f; }
    for (int j = i; j < N1; j += stride) { g_mp_c1[j] = 0.f; g_sp_c1[j] = 0.f; }
    for (int j = i; j < N2; j += stride) { g_mp_c2[j] = 0.f; g_sp_c2[j] = 0.f; }
    if (i < NHID) { g_mp_l1[i] = 0.f; g_sp_l1[i] = 0.f; }
    if (i < NOUT) g_mp_l2[i] = 0.f;
    if (i < (TSTEPS + 1) * NOUT) out[i] = 0.f;
}

// SnnInput: integrate image, fire, subtract threshold (no decay on input layer).
__global__ void input_kernel(const float* __restrict__ image) {
    int i = blockIdx.x * 256 + threadIdx.x;
    if (i >= NIN) return;
    float mp = g_mp_in[i] + image[i];
    float f = (mp >= THRES) ? 1.f : 0.f;
    g_s_in[i] = f;
    g_mp_in[i] = mp - THRES * f;
}

// SnnConv1: reads current-step input spikes. Thread per output element.
__global__ void conv1_kernel(const float* __restrict__ w1) {
    int i = blockIdx.x * 256 + threadIdx.x;
    if (i >= N1) return;
    int co = i / (D1 * D1);
    int r = i % (D1 * D1);
    int y = r / D1, x = r % D1;
    const float* __restrict__ w = w1 + co * (K1 * K1);
    float acc = 0.f;
#pragma unroll
    for (int ky = 0; ky < K1; ++ky) {
#pragma unroll
        for (int kx = 0; kx < K1; ++kx) {
            acc = fmaf(g_s_in[(y + ky) * DIM_IN + (x + kx)], w[ky * K1 + kx], acc);
        }
    }
    float mp = g_mp_c1[i] + acc;
    float f = (mp >= THRES) ? 1.f : 0.f;
    mp = (mp - THRES * f) * ((f > 0.f) ? 1.f : DECAY);
    g_mp_c1[i] = mp;
    g_sp_c1[i] = f;
}

// SnnConv2: reads previous-step conv1 spikes. Block = (one co, 256 spatial).
// Weights for this co staged in LDS (12.5 KB); spike reads hit L1/L2.
__global__ void __launch_bounds__(256) conv2_kernel(const float* __restrict__ w2) {
    __shared__ float wsh[C1 * K2 * K2];  // 3136 floats
    int co = blockIdx.x;
    int chunk = blockIdx.y;
    for (int j = threadIdx.x; j < C1 * K2 * K2; j += 256)
        wsh[j] = w2[co * C1 * K2 * K2 + j];
    __syncthreads();
    int sp = chunk * 256 + threadIdx.x;
    if (sp >= D2 * D2) return;
    int y = sp / D2, x = sp % D2;
    float acc = 0.f;
    for (int c = 0; c < C1; ++c) {
        const float* __restrict__ srow = g_sp_c1 + c * (D1 * D1) + y * D1 + x;
        const float* __restrict__ wr = wsh + c * (K2 * K2);
#pragma unroll
        for (int ky = 0; ky < K2; ++ky) {
#pragma unroll
            for (int kx = 0; kx < K2; ++kx) {
                acc = fmaf(srow[ky * D1 + kx], wr[ky * K2 + kx], acc);
            }
        }
    }
    int o = co * (D2 * D2) + sp;
    float mp = g_mp_c2[o] + acc;
    float f = (mp >= THRES) ? 1.f : 0.f;
    mp = (mp - THRES * f) * ((f > 0.f) ? 1.f : DECAY);
    g_mp_c2[o] = mp;
    g_sp_c2[o] = f;
}

// SnnLinear1: mp = mp*DECAY + w_l1 @ sp_c2(prev). Block per output row.
__global__ void __launch_bounds__(256) linear1_kernel(const float* __restrict__ wl1) {
    int row = blockIdx.x;  // 0..511
    const float4* __restrict__ w4 =
        (const float4*)(wl1 + (size_t)row * NFLAT);
    const float4* __restrict__ s4 = (const float4*)g_sp_c2;
    float acc = 0.f;
    // NFLAT/4 = 86528 = 256 * 338 exactly
    for (int j = threadIdx.x; j < NFLAT / 4; j += 256) {
        float4 w = w4[j];
        float4 s = s4[j];
        acc += w.x * s.x + w.y * s.y + w.z * s.z + w.w * s.w;
    }
    __shared__ float red[256];
    red[threadIdx.x] = acc;
    __syncthreads();
    for (int off = 128; off >= 1; off >>= 1) {
        if (threadIdx.x < off) red[threadIdx.x] += red[threadIdx.x + off];
        __syncthreads();
    }
    if (threadIdx.x == 0) {
        float mp = g_mp_l1[row] * DECAY + red[0];
        float f = (mp >= THRES) ? 1.f : 0.f;
        g_mp_l1[row] = mp - THRES * f;
        g_sp_l1[row] = f;
    }
}

// SnnLinear2: mp = mp*DECAY + w_l2 @ sp_l1(prev); writes output row t+1.
__global__ void linear2_kernel(const float* __restrict__ wl2, float* __restrict__ out, int t) {
    int o = threadIdx.x;
    if (o >= NOUT) return;
    float acc = 0.f;
    for (int k = 0; k < NHID; ++k)
        acc = fmaf(wl2[o * NHID + k], g_sp_l1[k], acc);
    float mp = g_mp_l2[o] * DECAY + acc;
    float f = (mp >= THRES) ? 1.f : 0.f;
    g_mp_l2[o] = mp - THRES * f;
    out[(t + 1) * NOUT + o] = f;
}

extern "C" void kernel_launch(void* const* d_in, const int* in_sizes, int n_in,
                              void* d_out, int out_size, void* d_ws, size_t ws_size,
                              hipStream_t stream) {
    const float* image = (const float*)d_in[0];
    const float* w_c1 = (const float*)d_in[1];
    const float* w_c2 = (const float*)d_in[2];
    const float* w_l1 = (const float*)d_in[3];
    const float* w_l2 = (const float*)d_in[4];
    float* out = (float*)d_out;

    init_kernel<<<512, 256, 0, stream>>>(out);

    for (int t = 0; t < TSTEPS; ++t) {
        // Reverse dependency order per step: consumers of previous-step
        // spikes run before this step's producers overwrite them.
        if (t >= 3) linear2_kernel<<<1, 64, 0, stream>>>(w_l2, out, t);
        if (t >= 2) linear1_kernel<<<512, 256, 0, stream>>>(w_l1);
        if (t >= 1) conv2_kernel<<<dim3(C2, (D2 * D2 + 255) / 256), 256, 0, stream>>>(w_c2);
        input_kernel<<<(NIN + 255) / 256, 256, 0, stream>>>(image);
        conv1_kernel<<<(N1 + 255) / 256, 256, 0, stream>>>(w_c1);
    }
}

// Round 2
// 5196.429 us; speedup vs baseline: 1.2929x; 1.2929x over previous
//
#include <hip/hip_runtime.h>

#define TSTEPS 20
constexpr float THRES = 1.0f;
constexpr float DECAY = 0.875f;  // (2^3-1)/2^3

constexpr int DIM_IN = 64;
constexpr int NIN = DIM_IN * DIM_IN;          // 4096
constexpr int C1 = 64, K1 = 7, D1 = 58;
constexpr int N1 = C1 * D1 * D1;              // 215296
constexpr int C2 = 128, K2 = 7, D2 = 52;
constexpr int N2 = C2 * D2 * D2;              // 346112
constexpr int NFLAT = N2;
constexpr int NHID = 512;
constexpr int NOUT = 10;

// Persistent state (zeroed every kernel_launch; harness doesn't re-poison).
__device__ float g_mp_in[NIN];
__device__ float g_s_in[NIN];
__device__ float g_mp_c1[N1];
__device__ float g_sp_c1[N1];   // conv1 spikes (read by conv2 next step)
__device__ float g_mp_c2[N2];
__device__ float g_sp_c2[N2];   // conv2 spikes (dense fallback path)
__device__ float g_mp_l1[NHID];
__device__ float g_sp_l1[NHID]; // linear1 spikes (read by linear2 next step)
__device__ float g_mp_l2[NOUT];
__device__ float g_dot[NHID];   // linear1 partial dot accumulator
__device__ int   g_nnz;         // active conv2 spike count
__device__ int   g_list[N2];    // active conv2 spike indices

__global__ void init_kernel(float* __restrict__ out) {
    int i = blockIdx.x * blockDim.x + threadIdx.x;
    int stride = gridDim.x * blockDim.x;
    for (int j = i; j < NIN; j += stride) { g_mp_in[j] = 0.f; g_s_in[j] = 0.f; }
    for (int j = i; j < N1; j += stride) { g_mp_c1[j] = 0.f; g_sp_c1[j] = 0.f; }
    for (int j = i; j < N2; j += stride) { g_mp_c2[j] = 0.f; g_sp_c2[j] = 0.f; }
    if (i < NHID) { g_mp_l1[i] = 0.f; g_sp_l1[i] = 0.f; g_dot[i] = 0.f; }
    if (i < NOUT) g_mp_l2[i] = 0.f;
    if (i < (TSTEPS + 1) * NOUT) out[i] = 0.f;
    if (i == 0) g_nnz = 0;
}

// One-time: w_l1 [512][NFLAT] -> wT [NFLAT][512] in d_ws. 32x32 LDS tiles.
__global__ void __launch_bounds__(256) transpose_kernel(const float* __restrict__ w,
                                                        float* __restrict__ wT) {
    __shared__ float tile[32][33];
    int bx = blockIdx.x * 32;            // along NFLAT
    int by = blockIdx.y * 32;            // along NHID
    int tx = threadIdx.x & 31, ty = threadIdx.x >> 5;  // ty 0..7
#pragma unroll
    for (int k = 0; k < 4; ++k)
        tile[ty + 8 * k][tx] = w[(size_t)(by + ty + 8 * k) * NFLAT + bx + tx];
    __syncthreads();
#pragma unroll
    for (int k = 0; k < 4; ++k)
        wT[(size_t)(bx + ty + 8 * k) * NHID + by + tx] = tile[tx][ty + 8 * k];
}

// SnnInput: integrate image, fire, subtract threshold.
__global__ void input_kernel(const float* __restrict__ image) {
    int i = blockIdx.x * 256 + threadIdx.x;
    if (i >= NIN) return;
    float mp = g_mp_in[i] + image[i];
    float f = (mp >= THRES) ? 1.f : 0.f;
    g_s_in[i] = f;
    g_mp_in[i] = mp - THRES * f;
}

// SnnConv1: reads current-step input spikes. Thread per output element.
__global__ void conv1_kernel(const float* __restrict__ w1) {
    int i = blockIdx.x * 256 + threadIdx.x;
    if (i >= N1) return;
    int co = i / (D1 * D1);
    int r = i % (D1 * D1);
    int y = r / D1, x = r % D1;
    const float* __restrict__ w = w1 + co * (K1 * K1);
    float acc = 0.f;
#pragma unroll
    for (int ky = 0; ky < K1; ++ky) {
#pragma unroll
        for (int kx = 0; kx < K1; ++kx) {
            acc = fmaf(g_s_in[(y + ky) * DIM_IN + (x + kx)], w[ky * K1 + kx], acc);
        }
    }
    float mp = g_mp_c1[i] + acc;
    float f = (mp >= THRES) ? 1.f : 0.f;
    mp = (mp - THRES * f) * ((f > 0.f) ? 1.f : DECAY);
    g_mp_c1[i] = mp;
    g_sp_c1[i] = f;
}

// SnnConv2: LDS-staged spikes (8 ch at a time), 4-outputs-in-y register
// blocking (196 FMA / 70 LDS reads per channel per thread), scalar weights.
// Block: co = blockIdx.x, 16-row band = blockIdx.y; 4 waves x 64 lanes.
constexpr int CH_TILE = 8;
__global__ void __launch_bounds__(256) conv2_kernel(const float* __restrict__ w2) {
    __shared__ float ssp[CH_TILE][22][58];  // 40.8 KB
    int co = blockIdx.x;
    int yb = blockIdx.y * 16;
    int g = threadIdx.x >> 6;   // wave id 0..3 -> rows yb+4g..yb+4g+3
    int l = threadIdx.x & 63;   // col
    int y0 = yb + 4 * g;
    bool active = (l < D2) && (y0 < D2);
    float acc[4] = {0.f, 0.f, 0.f, 0.f};
    for (int ct = 0; ct < C1; ct += CH_TILE) {
        __syncthreads();
        for (int e = threadIdx.x; e < CH_TILE * 22 * 58; e += 256) {
            int c = e / (22 * 58);
            int rem = e - c * (22 * 58);
            int r = rem / 58;
            int x = rem - r * 58;
            int gy = yb + r;
            ssp[c][r][x] = (gy < D1) ? g_sp_c1[(ct + c) * (D1 * D1) + gy * D1 + x] : 0.f;
        }
        __syncthreads();
        if (active) {
            for (int c = 0; c < CH_TILE; ++c) {
                float wr[49];
                const float* __restrict__ wp = w2 + ((size_t)co * C1 + (ct + c)) * 49;
#pragma unroll
                for (int k = 0; k < 49; ++k) wr[k] = wp[k];
#pragma unroll
                for (int r2 = 0; r2 < 10; ++r2) {
                    float v[7];
#pragma unroll
                    for (int kx = 0; kx < 7; ++kx) v[kx] = ssp[c][4 * g + r2][l + kx];
#pragma unroll
                    for (int o = 0; o < 4; ++o) {
                        int ky = r2 - o;
                        if (ky >= 0 && ky <= 6) {
#pragma unroll
                            for (int kx = 0; kx < 7; ++kx)
                                acc[o] = fmaf(v[kx], wr[ky * 7 + kx], acc[o]);
                        }
                    }
                }
            }
        }
    }
    if (active) {
#pragma unroll
        for (int o = 0; o < 4; ++o) {
            int idx = co * (D2 * D2) + (y0 + o) * D2 + l;
            float mp = g_mp_c2[idx] + acc[o];
            float f = (mp >= THRES) ? 1.f : 0.f;
            g_mp_c2[idx] = (mp - THRES * f) * ((f > 0.f) ? 1.f : DECAY);
            g_sp_c2[idx] = f;
            if (f > 0.f) {
                int pos = atomicAdd(&g_nnz, 1);
                g_list[pos] = idx;
            }
        }
    }
}

// SnnLinear1 sparse path: gather active columns of wT, atomically accumulate.
__global__ void __launch_bounds__(256) linear1_gather(const float* __restrict__ wT) {
    int nnz = g_nnz;
    const float2* __restrict__ wT2 = (const float2*)wT;
    int t = threadIdx.x;
    float2 a0 = {0.f, 0.f}, a1 = {0.f, 0.f}, a2 = {0.f, 0.f}, a3 = {0.f, 0.f};
    int stride = gridDim.x;
    int i = blockIdx.x;
    for (; i + 3 * stride < nnz; i += 4 * stride) {
        int j0 = g_list[i];
        int j1 = g_list[i + stride];
        int j2 = g_list[i + 2 * stride];
        int j3 = g_list[i + 3 * stride];
        float2 w0 = wT2[(size_t)j0 * 256 + t];
        float2 w1 = wT2[(size_t)j1 * 256 + t];
        float2 w2 = wT2[(size_t)j2 * 256 + t];
        float2 w3 = wT2[(size_t)j3 * 256 + t];
        a0.x += w0.x; a0.y += w0.y;
        a1.x += w1.x; a1.y += w1.y;
        a2.x += w2.x; a2.y += w2.y;
        a3.x += w3.x; a3.y += w3.y;
    }
    for (; i < nnz; i += stride) {
        float2 w0 = wT2[(size_t)g_list[i] * 256 + t];
        a0.x += w0.x; a0.y += w0.y;
    }
    float sx = a0.x + a1.x + a2.x + a3.x;
    float sy = a0.y + a1.y + a2.y + a3.y;
    atomicAdd(&g_dot[2 * t], sx);
    atomicAdd(&g_dot[2 * t + 1], sy);
}

// Finish linear1: decay, add dot, fire; reset accumulators for next step.
__global__ void linear1_finish() {
    int i = threadIdx.x;  // 512 threads
    float mp = g_mp_l1[i] * DECAY + g_dot[i];
    float f = (mp >= THRES) ? 1.f : 0.f;
    g_mp_l1[i] = mp - THRES * f;
    g_sp_l1[i] = f;
    g_dot[i] = 0.f;
    if (i == 0) g_nnz = 0;
}

// Dense fallback for linear1 (used only if ws too small for transpose).
__global__ void __launch_bounds__(256) linear1_dense(const float* __restrict__ wl1) {
    int row = blockIdx.x;
    const float4* __restrict__ w4 = (const float4*)(wl1 + (size_t)row * NFLAT);
    const float4* __restrict__ s4 = (const float4*)g_sp_c2;
    float acc = 0.f;
    for (int j = threadIdx.x; j < NFLAT / 4; j += 256) {
        float4 w = w4[j];
        float4 s = s4[j];
        acc += w.x * s.x + w.y * s.y + w.z * s.z + w.w * s.w;
    }
    __shared__ float red[256];
    red[threadIdx.x] = acc;
    __syncthreads();
    for (int off = 128; off >= 1; off >>= 1) {
        if (threadIdx.x < off) red[threadIdx.x] += red[threadIdx.x + off];
        __syncthreads();
    }
    if (threadIdx.x == 0) {
        float mp = g_mp_l1[row] * DECAY + red[0];
        float f = (mp >= THRES) ? 1.f : 0.f;
        g_mp_l1[row] = mp - THRES * f;
        g_sp_l1[row] = f;
    }
}

// SnnLinear2: mp = mp*DECAY + w_l2 @ sp_l1(prev); writes output row t+1.
__global__ void linear2_kernel(const float* __restrict__ wl2, float* __restrict__ out, int t) {
    int o = threadIdx.x;
    if (o >= NOUT) return;
    float acc = 0.f;
    for (int k = 0; k < NHID; ++k)
        acc = fmaf(wl2[o * NHID + k], g_sp_l1[k], acc);
    float mp = g_mp_l2[o] * DECAY + acc;
    float f = (mp >= THRES) ? 1.f : 0.f;
    g_mp_l2[o] = mp - THRES * f;
    out[(t + 1) * NOUT + o] = f;
}

extern "C" void kernel_launch(void* const* d_in, const int* in_sizes, int n_in,
                              void* d_out, int out_size, void* d_ws, size_t ws_size,
                              hipStream_t stream) {
    const float* image = (const float*)d_in[0];
    const float* w_c1 = (const float*)d_in[1];
    const float* w_c2 = (const float*)d_in[2];
    const float* w_l1 = (const float*)d_in[3];
    const float* w_l2 = (const float*)d_in[4];
    float* out = (float*)d_out;
    float* wT = (float*)d_ws;
    bool sparse = ws_size >= (size_t)NFLAT * NHID * sizeof(float);

    init_kernel<<<512, 256, 0, stream>>>(out);
    if (sparse)
        transpose_kernel<<<dim3(NFLAT / 32, NHID / 32), 256, 0, stream>>>(w_l1, wT);

    for (int t = 0; t < TSTEPS; ++t) {
        // Reverse dependency order per step: consumers of previous-step
        // spikes run before this step's producers overwrite them.
        // Spike front: s_in t>=1, sp_c1 t>=1, sp_c2 t>=2, sp_l1 t>=3, out t>=4.
        if (t >= 4) linear2_kernel<<<1, 64, 0, stream>>>(w_l2, out, t);
        if (t >= 3) {
            if (sparse) {
                linear1_gather<<<512, 256, 0, stream>>>(wT);
                linear1_finish<<<1, 512, 0, stream>>>();
            } else {
                linear1_dense<<<512, 256, 0, stream>>>(w_l1);
            }
        }
        if (t >= 2) conv2_kernel<<<dim3(C2, 4), 256, 0, stream>>>(w_c2);
        input_kernel<<<(NIN + 255) / 256, 256, 0, stream>>>(image);
        if (t >= 1) conv1_kernel<<<(N1 + 255) / 256, 256, 0, stream>>>(w_c1);
    }
}

// Round 3
// 3064.033 us; speedup vs baseline: 2.1926x; 1.6959x over previous
//
#include <hip/hip_runtime.h>

#define TSTEPS 20
constexpr float THRES = 1.0f;
constexpr float DECAY = 0.875f;  // (2^3-1)/2^3

constexpr int DIM_IN = 64;
constexpr int NIN = DIM_IN * DIM_IN;          // 4096
constexpr int C1 = 64, K1 = 7, D1 = 58;
constexpr int N1 = C1 * D1 * D1;              // 215296
constexpr int C2 = 128, K2 = 7, D2 = 52;
constexpr int N2 = C2 * D2 * D2;              // 346112
constexpr int NFLAT = N2;
constexpr int NHID = 512;
constexpr int NOUT = 10;
constexpr int KC = 16;          // conv2 K-split chunks
constexpr int CPC = C1 / KC;    // 4 input channels per chunk

// Persistent state (zeroed every kernel_launch; harness doesn't re-poison).
__device__ float g_mp_in[NIN];
__device__ float g_s_in[NIN];
__device__ float g_mp_c1[N1];
__device__ float g_sp_c1[N1];   // conv1 spikes (read by conv2 next step)
__device__ float g_mp_c2[N2];
__device__ float g_sp_c2[N2];   // conv2 spikes (dense fallback path)
__device__ float g_mp_l1[NHID];
__device__ float g_sp_l1[NHID]; // linear1 spikes (read by linear2 next step)
__device__ float g_mp_l2[NOUT];
__device__ float g_dot[NHID];   // linear1 dot accumulator
__device__ int   g_nnz;         // active conv2 spike count
__device__ int   g_list[N2];    // active conv2 spike indices

__global__ void init_kernel(float* __restrict__ out) {
    int i = blockIdx.x * blockDim.x + threadIdx.x;
    int stride = gridDim.x * blockDim.x;
    for (int j = i; j < NIN; j += stride) { g_mp_in[j] = 0.f; g_s_in[j] = 0.f; }
    for (int j = i; j < N1; j += stride) { g_mp_c1[j] = 0.f; g_sp_c1[j] = 0.f; }
    for (int j = i; j < N2; j += stride) { g_mp_c2[j] = 0.f; g_sp_c2[j] = 0.f; }
    if (i < NHID) { g_mp_l1[i] = 0.f; g_sp_l1[i] = 0.f; g_dot[i] = 0.f; }
    if (i < NOUT) g_mp_l2[i] = 0.f;
    if (i < (TSTEPS + 1) * NOUT) out[i] = 0.f;
    if (i == 0) g_nnz = 0;
}

// One-time: w_l1 [512][NFLAT] -> wT [NFLAT][512] in d_ws. 32x32 LDS tiles.
__global__ void __launch_bounds__(256) transpose_kernel(const float* __restrict__ w,
                                                        float* __restrict__ wT) {
    __shared__ float tile[32][33];
    int bx = blockIdx.x * 32;            // along NFLAT
    int by = blockIdx.y * 32;            // along NHID
    int tx = threadIdx.x & 31, ty = threadIdx.x >> 5;  // ty 0..7
#pragma unroll
    for (int k = 0; k < 4; ++k)
        tile[ty + 8 * k][tx] = w[(size_t)(by + ty + 8 * k) * NFLAT + bx + tx];
    __syncthreads();
#pragma unroll
    for (int k = 0; k < 4; ++k)
        wT[(size_t)(bx + ty + 8 * k) * NHID + by + tx] = tile[tx][ty + 8 * k];
}

// Fused small ops, one 512-thread block:
//   phase1: linear2 (t>=4) from OLD sp_l1 (LDS snapshot)
//   phase2: linear1 finish (3<=t<=18): decay + g_dot, fire, reset g_dot/g_nnz
//   phase3: input integrate+fire (t<=16)
__global__ void __launch_bounds__(512) fused_small(const float* __restrict__ wl2,
                                                   const float* __restrict__ image,
                                                   float* __restrict__ out, int t) {
    __shared__ float sp_old[NHID];
    int tid = threadIdx.x;
    if (t >= 4) sp_old[tid] = g_sp_l1[tid];
    __syncthreads();
    if (t >= 4) {
        int w = tid >> 6, lane = tid & 63;
        for (int o = w; o < NOUT; o += 8) {
            float a = 0.f;
#pragma unroll
            for (int k = lane; k < NHID; k += 64)
                a = fmaf(wl2[o * NHID + k], sp_old[k], a);
            for (int off = 32; off; off >>= 1) a += __shfl_down(a, off, 64);
            if (lane == 0) {
                float mp = g_mp_l2[o] * DECAY + a;
                float f = (mp >= THRES) ? 1.f : 0.f;
                g_mp_l2[o] = mp - THRES * f;
                out[(t + 1) * NOUT + o] = f;
            }
        }
    }
    if (t >= 3 && t <= 18) {
        float mp = g_mp_l1[tid] * DECAY + g_dot[tid];
        float f = (mp >= THRES) ? 1.f : 0.f;
        g_mp_l1[tid] = mp - THRES * f;
        g_sp_l1[tid] = f;
        g_dot[tid] = 0.f;
    }
    if (tid == 0) g_nnz = 0;
    if (t <= 16) {
#pragma unroll
        for (int j = tid; j < NIN; j += 512) {
            float mp = g_mp_in[j] + image[j];
            float f = (mp >= THRES) ? 1.f : 0.f;
            g_s_in[j] = f;
            g_mp_in[j] = mp - THRES * f;
        }
    }
}

// SnnConv1: block per co. Whole input-spike image staged in LDS (16 KB),
// weights uniform (scalar loads). ~14 outputs/thread.
__global__ void __launch_bounds__(256) conv1_kernel(const float* __restrict__ w1) {
    __shared__ float sim[NIN];
    int co = blockIdx.x;
    const float4* __restrict__ s4 = (const float4*)g_s_in;
    float4* d4 = (float4*)sim;
    for (int j = threadIdx.x; j < NIN / 4; j += 256) d4[j] = s4[j];
    __syncthreads();
    float w[49];
#pragma unroll
    for (int k = 0; k < 49; ++k) w[k] = w1[co * 49 + k];
    for (int idx = threadIdx.x; idx < D1 * D1; idx += 256) {
        int y = idx / D1, x = idx - y * D1;
        float a = 0.f;
#pragma unroll
        for (int ky = 0; ky < K1; ++ky)
#pragma unroll
            for (int kx = 0; kx < K1; ++kx)
                a = fmaf(sim[(y + ky) * DIM_IN + x + kx], w[ky * K1 + kx], a);
        int o = co * (D1 * D1) + idx;
        float mp = g_mp_c1[o] + a;
        float f = (mp >= THRES) ? 1.f : 0.f;
        g_mp_c1[o] = (mp - THRES * f) * ((f > 0.f) ? 1.f : DECAY);
        g_sp_c1[o] = f;
    }
}

// conv2 partial: K-split implicit GEMM. Block = 1 wave (64 lanes = x).
// Tile: 8 co (uniform -> scalar weights) x 4 y x 52 x, 4 input channels.
// grid: (16 co-tiles, 13 y-tiles, KC chunks).
__global__ void __launch_bounds__(64) conv2_partial(const float* __restrict__ w2,
                                                    float* __restrict__ part) {
    __shared__ float ssp[CPC][10][58];  // 9.28 KB
    int co0 = blockIdx.x * 8;
    int y0 = blockIdx.y * 4;
    int kc = blockIdx.z;
    int c0 = kc * CPC;
    int l = threadIdx.x;
    if (l < D1) {
#pragma unroll
        for (int c = 0; c < CPC; ++c)
#pragma unroll
            for (int r = 0; r < 10; ++r)
                ssp[c][r][l] = g_sp_c1[(c0 + c) * (D1 * D1) + (y0 + r) * D1 + l];
    }
    __syncthreads();
    float acc[8][4];
#pragma unroll
    for (int cl = 0; cl < 8; ++cl)
#pragma unroll
        for (int o = 0; o < 4; ++o) acc[cl][o] = 0.f;
    bool act = l < D2;
#pragma unroll 1
    for (int c = 0; c < CPC; ++c) {
#pragma unroll
        for (int ky = 0; ky < K2; ++ky) {
            // uniform weight slice: 8 co x 7 kx -> scalar loads
            float wv[8][7];
#pragma unroll
            for (int cl = 0; cl < 8; ++cl)
#pragma unroll
                for (int kx = 0; kx < 7; ++kx)
                    wv[cl][kx] = w2[((size_t)(co0 + cl) * C1 + (c0 + c)) * 49 + ky * 7 + kx];
            if (act) {
#pragma unroll
                for (int o = 0; o < 4; ++o) {
                    float v[7];
#pragma unroll
                    for (int kx = 0; kx < 7; ++kx) v[kx] = ssp[c][ky + o][l + kx];
#pragma unroll
                    for (int kx = 0; kx < 7; ++kx)
#pragma unroll
                        for (int cl = 0; cl < 8; ++cl)
                            acc[cl][o] = fmaf(v[kx], wv[cl][kx], acc[cl][o]);
                }
            }
        }
    }
    if (act) {
#pragma unroll
        for (int cl = 0; cl < 8; ++cl)
#pragma unroll
            for (int o = 0; o < 4; ++o)
                part[(size_t)kc * N2 + (co0 + cl) * (D2 * D2) + (y0 + o) * D2 + l] = acc[cl][o];
    }
}

// conv2 reduce: sum KC partials (deterministic order), membrane update, fire,
// decay, write spikes + nnz list. N2 = 1352 * 256 exactly.
__global__ void __launch_bounds__(256) conv2_reduce(const float* __restrict__ part) {
    int i = blockIdx.x * 256 + threadIdx.x;
    float s = 0.f;
#pragma unroll
    for (int k = 0; k < KC; ++k) s += part[(size_t)k * N2 + i];
    float mp = g_mp_c2[i] + s;
    float f = (mp >= THRES) ? 1.f : 0.f;
    g_mp_c2[i] = (mp - THRES * f) * ((f > 0.f) ? 1.f : DECAY);
    g_sp_c2[i] = f;
    if (f > 0.f) {
        int pos = atomicAdd(&g_nnz, 1);
        g_list[pos] = i;
    }
}

// SnnLinear1 sparse path: gather active columns of wT, atomically accumulate.
__global__ void __launch_bounds__(256) linear1_gather(const float* __restrict__ wT) {
    int nnz = g_nnz;
    const float2* __restrict__ wT2 = (const float2*)wT;
    int t = threadIdx.x;
    float2 a0 = {0.f, 0.f}, a1 = {0.f, 0.f}, a2 = {0.f, 0.f}, a3 = {0.f, 0.f};
    int stride = gridDim.x;
    int i = blockIdx.x;
    for (; i + 3 * stride < nnz; i += 4 * stride) {
        int j0 = g_list[i];
        int j1 = g_list[i + stride];
        int j2 = g_list[i + 2 * stride];
        int j3 = g_list[i + 3 * stride];
        float2 w0 = wT2[(size_t)j0 * 256 + t];
        float2 w1 = wT2[(size_t)j1 * 256 + t];
        float2 w2 = wT2[(size_t)j2 * 256 + t];
        float2 w3 = wT2[(size_t)j3 * 256 + t];
        a0.x += w0.x; a0.y += w0.y;
        a1.x += w1.x; a1.y += w1.y;
        a2.x += w2.x; a2.y += w2.y;
        a3.x += w3.x; a3.y += w3.y;
    }
    for (; i < nnz; i += stride) {
        float2 w0 = wT2[(size_t)g_list[i] * 256 + t];
        a0.x += w0.x; a0.y += w0.y;
    }
    float sx = a0.x + a1.x + a2.x + a3.x;
    float sy = a0.y + a1.y + a2.y + a3.y;
    atomicAdd(&g_dot[2 * t], sx);
    atomicAdd(&g_dot[2 * t + 1], sy);
}

// Dense fallback: writes g_dot[row]; fused_small's finish applies decay+fire.
__global__ void __launch_bounds__(256) linear1_dense(const float* __restrict__ wl1) {
    int row = blockIdx.x;
    const float4* __restrict__ w4 = (const float4*)(wl1 + (size_t)row * NFLAT);
    const float4* __restrict__ s4 = (const float4*)g_sp_c2;
    float acc = 0.f;
    for (int j = threadIdx.x; j < NFLAT / 4; j += 256) {
        float4 w = w4[j];
        float4 s = s4[j];
        acc += w.x * s.x + w.y * s.y + w.z * s.z + w.w * s.w;
    }
    __shared__ float red[256];
    red[threadIdx.x] = acc;
    __syncthreads();
    for (int off = 128; off >= 1; off >>= 1) {
        if (threadIdx.x < off) red[threadIdx.x] += red[threadIdx.x + off];
        __syncthreads();
    }
    if (threadIdx.x == 0) g_dot[row] = red[0];
}

extern "C" void kernel_launch(void* const* d_in, const int* in_sizes, int n_in,
                              void* d_out, int out_size, void* d_ws, size_t ws_size,
                              hipStream_t stream) {
    const float* image = (const float*)d_in[0];
    const float* w_c1 = (const float*)d_in[1];
    const float* w_c2 = (const float*)d_in[2];
    const float* w_l1 = (const float*)d_in[3];
    const float* w_l2 = (const float*)d_in[4];
    float* out = (float*)d_out;

    float* wT = (float*)d_ws;
    size_t wt_elems = (size_t)NFLAT * NHID;
    bool sparse = ws_size >= (wt_elems + (size_t)KC * N2) * sizeof(float);
    float* part = sparse ? wT + wt_elems : (float*)d_ws;

    init_kernel<<<512, 256, 0, stream>>>(out);
    if (sparse)
        transpose_kernel<<<dim3(NFLAT / 32, NHID / 32), 256, 0, stream>>>(w_l1, wT);

    // Live ranges (spike front + backward use analysis):
    //   input 0..16, conv1 1..16, conv2 2..17, linear1 3..18, linear2 4..19.
    for (int t = 0; t < TSTEPS; ++t) {
        if (t >= 3 && t <= 18) {
            if (sparse) linear1_gather<<<512, 256, 0, stream>>>(wT);
            else        linear1_dense<<<NHID, 256, 0, stream>>>(w_l1);
        }
        fused_small<<<1, 512, 0, stream>>>(w_l2, image, out, t);
        if (t >= 2 && t <= 17) {
            conv2_partial<<<dim3(C2 / 8, D2 / 4, KC), 64, 0, stream>>>(w_c2, part);
            conv2_reduce<<<N2 / 256, 256, 0, stream>>>(part);
        }
        if (t >= 1 && t <= 16) conv1_kernel<<<C1, 256, 0, stream>>>(w_c1);
    }
}

// Round 4
// 2474.656 us; speedup vs baseline: 2.7148x; 1.2382x over previous
//
#include <hip/hip_runtime.h>

#define TSTEPS 20
constexpr float THRES = 1.0f;
constexpr float DECAY = 0.875f;  // (2^3-1)/2^3

constexpr int DIM_IN = 64;
constexpr int NIN = DIM_IN * DIM_IN;          // 4096
constexpr int C1 = 64, K1 = 7, D1 = 58;
constexpr int N1 = C1 * D1 * D1;              // 215296
constexpr int C2 = 128, K2 = 7, D2 = 52;
constexpr int N2 = C2 * D2 * D2;              // 346112
constexpr int NFLAT = N2;
constexpr int NHID = 512;
constexpr int NOUT = 10;
constexpr int KC = 16;          // conv2 K-split chunks
constexpr int CPC = C1 / KC;    // 4 input channels per chunk

// mega1 block roles: [0,512) gather | [512,1344) conv2-partial | 1344 misc
constexpr int NB_GATHER = 512;
constexpr int NB_PART = 832;     // 3328 wave-tasks / 4 waves
constexpr int NB1 = NB_GATHER + NB_PART + 1;   // 1345
// mega2 block roles: [0,1352) reduce | [1352,1416) conv1 | 1416 finish
constexpr int NB_RED = N2 / 256; // 1352
constexpr int NB2 = NB_RED + C1 + 1;           // 1417

// Persistent state (zeroed every kernel_launch; harness doesn't re-poison).
__device__ float g_mp_in[NIN];
__device__ float g_s_in[NIN];
__device__ float g_mp_c1[N1];
__device__ float g_sp_c1[2][N1];   // double-buffered by step parity
__device__ float g_mp_c2[N2];
__device__ float g_sp_c2[N2];      // dense fallback path only
__device__ float g_mp_l1[NHID];
__device__ float g_sp_l1[NHID];
__device__ float g_mp_l2[NOUT];
__device__ float g_dot[NHID];      // linear1 dot accumulator
__device__ int   g_nnz[2];         // double-buffered spike counts
__device__ int   g_list[2][N2];    // double-buffered spike index lists

__global__ void init_kernel(float* __restrict__ out) {
    int i = blockIdx.x * blockDim.x + threadIdx.x;
    int stride = gridDim.x * blockDim.x;
    for (int j = i; j < NIN; j += stride) { g_mp_in[j] = 0.f; g_s_in[j] = 0.f; }
    for (int j = i; j < N1; j += stride) {
        g_mp_c1[j] = 0.f; g_sp_c1[0][j] = 0.f; g_sp_c1[1][j] = 0.f;
    }
    for (int j = i; j < N2; j += stride) { g_mp_c2[j] = 0.f; g_sp_c2[j] = 0.f; }
    if (i < NHID) { g_mp_l1[i] = 0.f; g_sp_l1[i] = 0.f; g_dot[i] = 0.f; }
    if (i < NOUT) g_mp_l2[i] = 0.f;
    if (i < (TSTEPS + 1) * NOUT) out[i] = 0.f;
    if (i < 2) g_nnz[i] = 0;
}

// One-time: w_l1 [512][NFLAT] -> wT [NFLAT][512]. 64x64 tiles, 256B/wave
// coalescing on both load and store. NFLAT = 64*5408, NHID = 64*8 exactly.
__global__ void __launch_bounds__(256) transpose_kernel(const float* __restrict__ w,
                                                        float* __restrict__ wT) {
    __shared__ float tile[64][65];
    int bx = blockIdx.x * 64;            // along NFLAT
    int by = blockIdx.y * 64;            // along NHID
    int tx = threadIdx.x & 63, ty = threadIdx.x >> 6;  // ty 0..3
#pragma unroll
    for (int k = 0; k < 16; ++k)
        tile[ty + 4 * k][tx] = w[(size_t)(by + ty + 4 * k) * NFLAT + bx + tx];
    __syncthreads();
#pragma unroll
    for (int k = 0; k < 16; ++k)
        wT[(size_t)(bx + ty + 4 * k) * NHID + by + tx] = tile[tx][ty + 4 * k];
}

// ---- D1(t): gather(t) || conv2_partial(t) || {input(t), linear2(t), reset} ----
// All roles read only state produced at step t-1 (or earlier) -> no intra-
// dispatch hazards. Partial uses per-wave LDS slices with NO barrier.
__global__ void __launch_bounds__(256) mega1(const float* __restrict__ w2,
                                             const float* __restrict__ wT,
                                             const float* __restrict__ wl2,
                                             const float* __restrict__ image,
                                             float* __restrict__ part,
                                             float* __restrict__ out,
                                             int t, int sparse) {
    __shared__ float ssp[4][CPC][10][58];  // 37.1 KB (partial role)
    int bid = blockIdx.x, tid = threadIdx.x;

    if (bid < NB_GATHER) {
        // ---- linear1 sparse gather: sum active columns of wT into g_dot ----
        if (!sparse || t < 3 || t > 18) return;
        int p = (t + 1) & 1;               // parity of step t-1
        int nnz = g_nnz[p];
        const int* __restrict__ list = g_list[p];
        const float2* __restrict__ wT2 = (const float2*)wT;
        int h = tid;                       // hidden-unit pair 0..255
        float2 a0 = {0.f, 0.f}, a1 = {0.f, 0.f}, a2 = {0.f, 0.f}, a3 = {0.f, 0.f};
        int i = bid;
        for (; i + 3 * NB_GATHER < nnz; i += 4 * NB_GATHER) {
            int j0 = list[i];
            int j1 = list[i + NB_GATHER];
            int j2 = list[i + 2 * NB_GATHER];
            int j3 = list[i + 3 * NB_GATHER];
            float2 w0 = wT2[(size_t)j0 * 256 + h];
            float2 w1 = wT2[(size_t)j1 * 256 + h];
            float2 w2v = wT2[(size_t)j2 * 256 + h];
            float2 w3 = wT2[(size_t)j3 * 256 + h];
            a0.x += w0.x; a0.y += w0.y;
            a1.x += w1.x; a1.y += w1.y;
            a2.x += w2v.x; a2.y += w2v.y;
            a3.x += w3.x; a3.y += w3.y;
        }
        for (; i < nnz; i += NB_GATHER) {
            float2 w0 = wT2[(size_t)list[i] * 256 + h];
            a0.x += w0.x; a0.y += w0.y;
        }
        atomicAdd(&g_dot[2 * h], a0.x + a1.x + a2.x + a3.x);
        atomicAdd(&g_dot[2 * h + 1], a0.y + a1.y + a2.y + a3.y);
    } else if (bid < NB_GATHER + NB_PART) {
        // ---- conv2 partial: 4 independent wave-tasks per block ----
        if (t < 2 || t > 17) return;
        int wid = tid >> 6, lane = tid & 63;
        int wt = __builtin_amdgcn_readfirstlane((bid - NB_GATHER) * 4 + wid);
        int kc = wt & 15;                  // 3328 = 13<<8; wt=(yt*16+cot)*16+kc
        int cot = (wt >> 4) & 15;
        int yt = wt >> 8;                  // 0..12
        int co0 = cot * 8, y0 = yt * 4, c0 = kc * CPC;
        const float* __restrict__ sp = g_sp_c1[(t + 1) & 1];  // step t-1 spikes
        for (int e = lane; e < CPC * 10 * 58; e += 64) {
            int c = e / 580;
            int rem = e - c * 580;
            int r = rem / 58, x = rem - r * 58;
            ssp[wid][c][r][x] = sp[(c0 + c) * (D1 * D1) + (y0 + r) * D1 + x];
        }
        // no __syncthreads: each wave reads only its own LDS slice.
        float acc[8][4] = {};
        bool act = lane < D2;
#pragma unroll 1
        for (int c = 0; c < CPC; ++c) {
#pragma unroll
            for (int ky = 0; ky < K2; ++ky) {
                float wv[8][7];  // block... wave-uniform -> scalar loads
#pragma unroll
                for (int cl = 0; cl < 8; ++cl)
#pragma unroll
                    for (int kx = 0; kx < 7; ++kx)
                        wv[cl][kx] = w2[((size_t)(co0 + cl) * C1 + c0 + c) * 49 + ky * 7 + kx];
                if (act) {
#pragma unroll
                    for (int o = 0; o < 4; ++o) {
                        float v[7];
#pragma unroll
                        for (int kx = 0; kx < 7; ++kx) v[kx] = ssp[wid][c][o + ky][lane + kx];
#pragma unroll
                        for (int kx = 0; kx < 7; ++kx)
#pragma unroll
                            for (int cl = 0; cl < 8; ++cl)
                                acc[cl][o] = fmaf(v[kx], wv[cl][kx], acc[cl][o]);
                    }
                }
            }
        }
        if (act) {
#pragma unroll
            for (int cl = 0; cl < 8; ++cl)
#pragma unroll
                for (int o = 0; o < 4; ++o)
                    part[(size_t)kc * N2 + (co0 + cl) * (D2 * D2) + (y0 + o) * D2 + lane] =
                        acc[cl][o];
        }
    } else {
        // ---- misc: nnz reset, input integrate/fire, linear2 ----
        if (tid == 0) g_nnz[t & 1] = 0;    // before reduce(t) increments in D2(t)
        if (t <= 16) {
            for (int j = tid; j < NIN; j += 256) {
                float mp = g_mp_in[j] + image[j];
                float f = (mp >= THRES) ? 1.f : 0.f;
                g_s_in[j] = f;
                g_mp_in[j] = mp - THRES * f;   // SnnInput: no decay
            }
        }
        if (t >= 4) {
            int w = tid >> 6, lane = tid & 63;
            for (int o = w; o < NOUT; o += 4) {
                float a = 0.f;
#pragma unroll
                for (int k = lane; k < NHID; k += 64)
                    a = fmaf(wl2[o * NHID + k], g_sp_l1[k], a);  // sp_l1 from t-1
                for (int off = 32; off; off >>= 1) a += __shfl_down(a, off, 64);
                if (lane == 0) {
                    float mp = g_mp_l2[o] * DECAY + a;
                    float f = (mp >= THRES) ? 1.f : 0.f;
                    g_mp_l2[o] = mp - THRES * f;
                    out[(t + 1) * NOUT + o] = f;
                }
            }
        }
    }
}

// ---- D2(t): conv2_reduce(t) || conv1(t) || linear1_finish(t) ----
__global__ void __launch_bounds__(256) mega2(const float* __restrict__ w1,
                                             const float* __restrict__ part,
                                             int t) {
    __shared__ float sim[NIN];  // 16 KB (conv1 role)
    int bid = blockIdx.x, tid = threadIdx.x;

    if (bid < NB_RED) {
        // ---- conv2 reduce: deterministic KC-sum, fire, decay, spike list ----
        if (t < 2 || t > 17) return;
        int i = bid * 256 + tid;
        float s = 0.f;
#pragma unroll
        for (int k = 0; k < KC; ++k) s += part[(size_t)k * N2 + i];
        float mp = g_mp_c2[i] + s;
        float f = (mp >= THRES) ? 1.f : 0.f;
        g_mp_c2[i] = (mp - THRES * f) * ((f > 0.f) ? 1.f : DECAY);
        g_sp_c2[i] = f;
        if (f > 0.f) {
            int pos = atomicAdd(&g_nnz[t & 1], 1);
            g_list[t & 1][pos] = i;
        }
    } else if (bid < NB_RED + C1) {
        // ---- conv1: whole spike image in LDS, uniform weights ----
        if (t < 1 || t > 16) return;
        int co = bid - NB_RED;
        const float4* __restrict__ s4 = (const float4*)g_s_in;
        float4* d4 = (float4*)sim;
        for (int j = tid; j < NIN / 4; j += 256) d4[j] = s4[j];
        __syncthreads();
        float w[49];
#pragma unroll
        for (int k = 0; k < 49; ++k) w[k] = w1[co * 49 + k];
        float* __restrict__ spb = g_sp_c1[t & 1];
        for (int idx = tid; idx < D1 * D1; idx += 256) {
            int y = idx / D1, x = idx - y * D1;
            float a = 0.f;
#pragma unroll
            for (int ky = 0; ky < K1; ++ky)
#pragma unroll
                for (int kx = 0; kx < K1; ++kx)
                    a = fmaf(sim[(y + ky) * DIM_IN + x + kx], w[ky * K1 + kx], a);
            int o = co * (D1 * D1) + idx;
            float mp = g_mp_c1[o] + a;
            float f = (mp >= THRES) ? 1.f : 0.f;
            g_mp_c1[o] = (mp - THRES * f) * ((f > 0.f) ? 1.f : DECAY);
            spb[o] = f;
        }
    } else {
        // ---- linear1 finish: decay + dot, fire, reset dot ----
        if (t < 3 || t > 18) return;
        for (int i = tid; i < NHID; i += 256) {
            float mp = g_mp_l1[i] * DECAY + g_dot[i];
            float f = (mp >= THRES) ? 1.f : 0.f;
            g_mp_l1[i] = mp - THRES * f;
            g_sp_l1[i] = f;
            g_dot[i] = 0.f;
        }
    }
}

// Dense fallback (ws too small for wT): writes g_dot[row]; finish applies it.
__global__ void __launch_bounds__(256) linear1_dense(const float* __restrict__ wl1) {
    int row = blockIdx.x;
    const float4* __restrict__ w4 = (const float4*)(wl1 + (size_t)row * NFLAT);
    const float4* __restrict__ s4 = (const float4*)g_sp_c2;
    float acc = 0.f;
    for (int j = threadIdx.x; j < NFLAT / 4; j += 256) {
        float4 w = w4[j];
        float4 s = s4[j];
        acc += w.x * s.x + w.y * s.y + w.z * s.z + w.w * s.w;
    }
    __shared__ float red[256];
    red[threadIdx.x] = acc;
    __syncthreads();
    for (int off = 128; off >= 1; off >>= 1) {
        if (threadIdx.x < off) red[threadIdx.x] += red[threadIdx.x + off];
        __syncthreads();
    }
    if (threadIdx.x == 0) g_dot[row] = red[0];
}

extern "C" void kernel_launch(void* const* d_in, const int* in_sizes, int n_in,
                              void* d_out, int out_size, void* d_ws, size_t ws_size,
                              hipStream_t stream) {
    const float* image = (const float*)d_in[0];
    const float* w_c1 = (const float*)d_in[1];
    const float* w_c2 = (const float*)d_in[2];
    const float* w_l1 = (const float*)d_in[3];
    const float* w_l2 = (const float*)d_in[4];
    float* out = (float*)d_out;

    float* wT = (float*)d_ws;
    size_t wt_elems = (size_t)NFLAT * NHID;
    bool sparse = ws_size >= (wt_elems + (size_t)KC * N2) * sizeof(float);
    float* part = sparse ? wT + wt_elems : (float*)d_ws;

    init_kernel<<<512, 256, 0, stream>>>(out);
    if (sparse)
        transpose_kernel<<<dim3(NFLAT / 64, NHID / 64), 256, 0, stream>>>(w_l1, wT);

    // Live ranges: input 0..16, conv1 1..16, conv2 2..17, l1 3..18, l2 4..19.
    for (int t = 0; t < TSTEPS; ++t) {
        if (!sparse && t >= 3 && t <= 18)
            linear1_dense<<<NHID, 256, 0, stream>>>(w_l1);
        mega1<<<NB1, 256, 0, stream>>>(w_c2, wT, w_l2, image, part, out, t,
                                       sparse ? 1 : 0);
        if (t >= 1 && t <= 18)
            mega2<<<NB2, 256, 0, stream>>>(w_c1, part, t);
    }
}